// Round 5
// baseline (108.580 us; speedup 1.0000x reference)
//
#include <hip/hip_runtime.h>
#include <hip/hip_cooperative_groups.h>
#include <math.h>

namespace cg = cooperative_groups;

// B=16, T=64, R=256, C=16, D=16, O(=in_dim)=16, NUM_ITERATIONS=3
//
// Factorization: u_hat[b,t,r,c,o] = Wsum[r,c,o]*usum[b,t]
//   Wsum[r,c,o] = sum_d W[r,c,d,o], usum[b,t] = sum_i ui[b,t,i]
// Per iter: cij = softmax_c(bij); S[b,c,o] = sum_r cij*Wsum; NS = sum_o S^2
//   bij += (sum_o Wsum[r,c,o]*S[c,o]) * Ts,  Ts = sum_t us^2*squash_scale(us^2*NS)
// Output: v[b,t,c,o] = squash_scale(us^2*NS)*us*S[c,o]
//
// Single cooperative launch: 256 blocks (=CUs) x 256 threads.
// Phase0 computes Wsum (block=r); after grid.sync blocks become (b,c), each
// holding Wsum[:,c,:] in LDS for all 3 iterations. bij layout (b,c,r) for
// coalesced column writes; double-buffered across grid.syncs (R2 race lesson).

#define OFF_WSUM  0        // [256][16][16] (r, c, o)
#define OFF_BIJ1  65536    // [16][16][256] (b, c, r)
#define OFF_BIJ2  131072   // [16][16][256]

__device__ __forceinline__ float squash_scale(float n2) {
    return n2 / (1.0f + n2) * rsqrtf(n2 + 1e-9f);
}

__global__ void __launch_bounds__(256, 1) caps_fused(
    const float* __restrict__ ui, const float* __restrict__ W,
    float* __restrict__ out, float* __restrict__ ws)
{
    cg::grid_group grid = cg::this_grid();
    const int tid = threadIdx.x;
    const int bid = blockIdx.x;

    // ---- Phase 0: Wsum[p,c,o] = sum_d W[p,c,d,o]; block p = bid ----
    {
        const int cc = tid >> 4, oo = tid & 15;
        const float* base = W + bid * 4096 + cc * 256 + oo;
        float s = 0.f;
#pragma unroll
        for (int d = 0; d < 16; ++d) s += base[d * 16];
        ws[OFF_WSUM + bid * 256 + tid] = s;
    }
    grid.sync();

    // ---- Routing: block = (b, c) ----
    const int b = bid >> 4, c = bid & 15;

    __shared__ float wsm[256][17];   // Wsum[r][o], stride 17 -> <=2-way banks
    __shared__ float part[16][17];
    __shared__ float usum_sh[64];
    __shared__ float cij_sh[256];
    __shared__ float S_sh[16];
    __shared__ float Ts_sh[1];

    // Wsum[:,c,:] -> LDS (thread = r)
    {
        const float4* src = (const float4*)(ws + OFF_WSUM + tid * 256 + c * 16);
        float tmp[16];
        ((float4*)tmp)[0] = src[0]; ((float4*)tmp)[1] = src[1];
        ((float4*)tmp)[2] = src[2]; ((float4*)tmp)[3] = src[3];
#pragma unroll
        for (int o = 0; o < 16; ++o) wsm[tid][o] = tmp[o];
    }
    // usum[b,t] (threads 0..63)
    if (tid < 64) {
        const float4* u4 = (const float4*)(ui + b * 1024 + tid * 16);
        float4 a = u4[0], e = u4[1], f = u4[2], g = u4[3];
        usum_sh[tid] = ((a.x + a.y) + (a.z + a.w)) + ((e.x + e.y) + (e.z + e.w))
                     + ((f.x + f.y) + (f.z + f.w)) + ((g.x + g.y) + (g.z + g.w));
    }
    __syncthreads();

    float ownLogit = 0.f;            // logit of (r=tid, own c); 0 at iter 0

    for (int it = 0; it < 3; ++it) {
        // A: softmax over c of bij[b,:,r=tid] (skip at it0: uniform)
        if (it > 0) {
            const float* src = ws + (it == 1 ? OFF_BIJ1 : OFF_BIJ2) + b * 4096;
            float v[16];
#pragma unroll
            for (int c2 = 0; c2 < 16; ++c2) v[c2] = src[c2 * 256 + tid];
            ownLogit = v[c];
            float m = v[0];
#pragma unroll
            for (int k = 1; k < 16; ++k) m = fmaxf(m, v[k]);
            float sum = 0.f;
#pragma unroll
            for (int k = 0; k < 16; ++k) { v[k] = __expf(v[k] - m); sum += v[k]; }
            cij_sh[tid] = v[c] / sum;
            __syncthreads();
        }

        // B: S[o] = sum_r cij[r]*wsm[r][o]; thread=(rs,o), 16-way r split
        {
            const int oo = tid & 15, rs = tid >> 4;
            float acc = 0.f;
#pragma unroll
            for (int j = 0; j < 16; ++j) {
                const int r = rs * 16 + j;
                const float cv = (it == 0) ? 1.0f : cij_sh[r];
                acc += cv * wsm[r][oo];
            }
            part[oo][rs] = acc;
        }
        __syncthreads();
        if (tid < 16) {
            float s = 0.f;
#pragma unroll
            for (int k = 0; k < 16; ++k) s += part[tid][k];
            S_sh[tid] = (it == 0) ? s * (1.0f / 16.0f) : s;
        }
        __syncthreads();

        if (it < 2) {
            // C: Ts = sum_t us^2*squash_scale(us^2*NS); NS recomputed per lane
            if (tid < 64) {
                float ns = 0.f;
#pragma unroll
                for (int o = 0; o < 16; ++o) { float s = S_sh[o]; ns += s * s; }
                const float us = usum_sh[tid];
                const float us2 = us * us;
                float v = us2 * squash_scale(us2 * ns);
#pragma unroll
                for (int off = 32; off > 0; off >>= 1) v += __shfl_down(v, off, 64);
                if (tid == 0) Ts_sh[0] = v;
            }
            __syncthreads();
            // D: bijDst[b,c,r] = ownLogit + (sum_o wsm[r][o]*S[o])*Ts (coalesced)
            {
                float dotv = 0.f;
#pragma unroll
                for (int o = 0; o < 16; ++o) dotv += wsm[tid][o] * S_sh[o];
                ws[(it == 0 ? OFF_BIJ1 : OFF_BIJ2) + b * 4096 + c * 256 + tid]
                    = ownLogit + dotv * Ts_sh[0];
            }
            grid.sync();
        } else {
            // E: v[b,t,c,o] = squash_scale(us^2*NS)*us*S[o]; thread=(t,oq)
            const int t = tid >> 2, oq = tid & 3;
            float ns = 0.f;
#pragma unroll
            for (int o = 0; o < 16; ++o) { float s = S_sh[o]; ns += s * s; }
            const float us = usum_sh[t];
            const float n2 = us * us * ns;
            const float f = squash_scale(n2) * us;
            float4 ov;
            ov.x = f * S_sh[oq * 4 + 0];
            ov.y = f * S_sh[oq * 4 + 1];
            ov.z = f * S_sh[oq * 4 + 2];
            ov.w = f * S_sh[oq * 4 + 3];
            ((float4*)(out + (((b * 64 + t) * 16 + c) << 4)))[oq] = ov;
        }
    }
}

extern "C" void kernel_launch(void* const* d_in, const int* in_sizes, int n_in,
                              void* d_out, int out_size, void* d_ws, size_t ws_size,
                              hipStream_t stream) {
    const float* ui = (const float*)d_in[0];   // [16,64,16]
    const float* W  = (const float*)d_in[1];   // [1,256,16,16,16]
    float* out = (float*)d_out;                // [16,64,16,16]
    float* ws  = (float*)d_ws;

    void* args[] = { (void*)&ui, (void*)&W, (void*)&out, (void*)&ws };
    hipLaunchCooperativeKernel((void*)caps_fused, dim3(256), dim3(256),
                               args, 0, stream);
}

// Round 6
// 49.382 us; speedup vs baseline: 2.1987x; 2.1987x over previous
//
#include <hip/hip_runtime.h>
#include <math.h>

// B=16, T=64, R=256, C=16, D=16, O(=in_dim)=16, NUM_ITERATIONS=3
//
// Factorization: u_hat[b,t,r,c,o] = Wsum[r,c,o]*usum[b,t]
//   Wsum[r,c,o] = sum_d W[r,c,d,o], usum[b,t] = sum_i ui[b,t,i]
// Per iter: cij = softmax_c(bij); S[c,o] = sum_r cij*Wsum; NS[c] = sum_o S^2
//   bij[r,c] += (sum_o Wsum[r,c,o]*S[c,o]) * Ts[c],
//   Ts[c] = sum_t us^2*squash_scale(us^2*NS[c])
// Output: v[b,t,c,o] = squash_scale(us^2*NS[c])*us*S[c,o]
//
// Structure (R5 lesson: grid.sync = 28us each -> dead; R4 lesson: launches
// dominate): 2 launches. k2 = 16 blocks (one per b; the all-r reduction in S
// forces b-granularity). Wsum r<128 half LDS-resident (stride-257, conflict-
// free); r>=128 streamed from L2 in WsumT (co,r) layout (coalesced).
// Logits live in LDS, renormalized in place (l -= m+logZ); cij = exp(l).

#define OFF_WT 0   // WsumT [co=c*16+o][r]  256x256 floats

__device__ __forceinline__ float squash_scale(float n2) {
    return n2 / (1.0f + n2) * rsqrtf(n2 + 1e-9f);
}

// K1: WsumT[co][r] = sum_d W[r,c,d,o]. grid 256x256.
__global__ void k1_prep(const float* __restrict__ W, float* __restrict__ ws) {
    const int r = blockIdx.x, tid = threadIdx.x;   // tid = c*16+o
    const int c = tid >> 4, o = tid & 15;
    const float* base = W + r * 4096 + c * 256 + o;
    float s = 0.f;
#pragma unroll
    for (int d = 0; d < 16; ++d) s += base[d * 16];
    ws[OFF_WT + tid * 256 + r] = s;
}

// K2: full routing, one block per b. grid 16 x 1024.
__global__ void __launch_bounds__(1024, 1) k2_route(
    const float* __restrict__ ui, const float* __restrict__ ws,
    float* __restrict__ out)
{
    __shared__ float wsm[128][257];        // Wsum[r<128][co], pad 257
    __shared__ float bl[16][257];          // normalized logits [c][r]
    __shared__ float part[256][5];         // B-phase partials [co][rs]
    __shared__ __align__(16) float S_sh[256];
    __shared__ float NS_sh[16];
    __shared__ float Ts_sh[16];
    __shared__ float usum_sh[64];

    const int b = blockIdx.x, tid = threadIdx.x;

    // usum[b,t] (wave 0)
    if (tid < 64) {
        const float4* u4 = (const float4*)(ui + b * 1024 + tid * 16);
        float4 a = u4[0], e = u4[1], f = u4[2], g = u4[3];
        usum_sh[tid] = ((a.x + a.y) + (a.z + a.w)) + ((e.x + e.y) + (e.z + e.w))
                     + ((f.x + f.y) + (f.z + f.w)) + ((g.x + g.y) + (g.z + g.w));
    }
    // wsm fill: r<128 from WsumT, float4 over r (coalesced), scatter to LDS
#pragma unroll
    for (int p = 0; p < 8; ++p) {
        const int lin = p * 1024 + tid;    // float4 id; 32 float4 per co row
        const int co = lin >> 5, r4 = lin & 31;
        const float4 v = ((const float4*)(ws + OFF_WT + co * 256))[r4];
        const int r = r4 * 4;
        wsm[r][co] = v.x; wsm[r + 1][co] = v.y;
        wsm[r + 2][co] = v.z; wsm[r + 3][co] = v.w;
    }
    __syncthreads();

    for (int it = 0; it < 3; ++it) {
        // A: renormalize logits in place; after this exp(bl) == cij. (skip it0)
        if (it > 0) {
            if (tid < 256) {
                float v[16];
#pragma unroll
                for (int c = 0; c < 16; ++c) v[c] = bl[c][tid];
                float m = v[0];
#pragma unroll
                for (int c = 1; c < 16; ++c) m = fmaxf(m, v[c]);
                float z = 0.f;
#pragma unroll
                for (int c = 0; c < 16; ++c) z += __expf(v[c] - m);
                const float sub = m + __logf(z);
#pragma unroll
                for (int c = 0; c < 16; ++c) bl[c][tid] = v[c] - sub;
            }
            __syncthreads();
        }

        // B: S[co] = sum_r cij[r]*Wsum[r][co]; rs = wave-quad (0,1: LDS; 2,3: L2)
        {
            const int rs = tid >> 8;       // wave-uniform
            const int co = tid & 255;
            const int c = co >> 4;
            const int r0 = rs * 64;
            float acc = 0.f;
            if (it == 0) {
                if (rs < 2) {
#pragma unroll
                    for (int j = 0; j < 64; ++j) acc += wsm[r0 + j][co];
                } else {
                    const float4* src = (const float4*)(ws + OFF_WT + co * 256 + r0);
#pragma unroll
                    for (int q = 0; q < 16; ++q) {
                        float4 w = src[q];
                        acc += (w.x + w.y) + (w.z + w.w);
                    }
                }
            } else {
                if (rs < 2) {
                    for (int j = 0; j < 64; ++j)
                        acc += __expf(bl[c][r0 + j]) * wsm[r0 + j][co];
                } else {
                    const float4* src = (const float4*)(ws + OFF_WT + co * 256 + r0);
                    for (int q = 0; q < 16; ++q) {
                        float4 w = src[q];
                        const int rr = r0 + q * 4;
                        acc += __expf(bl[c][rr]) * w.x + __expf(bl[c][rr + 1]) * w.y
                             + __expf(bl[c][rr + 2]) * w.z + __expf(bl[c][rr + 3]) * w.w;
                    }
                }
            }
            part[co][rs] = acc;
        }
        __syncthreads();
        if (tid < 256) {
            const float s = (part[tid][0] + part[tid][1]) + (part[tid][2] + part[tid][3]);
            S_sh[tid] = (it == 0) ? s * (1.0f / 16.0f) : s;
        }
        __syncthreads();
        if (tid < 16) {
            float ns = 0.f;
#pragma unroll
            for (int o = 0; o < 16; ++o) { const float s = S_sh[tid * 16 + o]; ns += s * s; }
            NS_sh[tid] = ns;
        }
        __syncthreads();

        if (it < 2) {
            // Ts[c]: one wave per c, shuffle reduce over t
            {
                const int c = tid >> 6, t = tid & 63;
                const float us = usum_sh[t];
                const float us2 = us * us;
                float v = us2 * squash_scale(us2 * NS_sh[c]);
#pragma unroll
                for (int off = 32; off > 0; off >>= 1) v += __shfl_down(v, off, 64);
                if (t == 0) Ts_sh[c] = v;
            }
            __syncthreads();
            // E: bl[c][r] += (sum_o Wsum[r,c,o]*S[c,o]) * Ts[c]
            {
                const int r = tid & 255;
                const int ch = tid >> 8;   // wave-uniform; r-range wave-uniform
#pragma unroll
                for (int k = 0; k < 4; ++k) {
                    const int c = k * 4 + ch;
                    float g = 0.f;
                    if (r < 128) {
#pragma unroll
                        for (int o = 0; o < 16; ++o)
                            g += wsm[r][c * 16 + o] * S_sh[c * 16 + o];
                    } else {
#pragma unroll
                        for (int o = 0; o < 16; ++o)
                            g += ws[OFF_WT + (c * 16 + o) * 256 + r] * S_sh[c * 16 + o];
                    }
                    const float d = g * Ts_sh[c];
                    bl[c][r] = (it == 0) ? d : bl[c][r] + d;
                }
            }
            __syncthreads();
        } else {
            // Output: v[b,t,c,o] = squash_scale(us^2*NS[c])*us*S[c,o]
            const int t = tid >> 4, c = tid & 15;
            const float us = usum_sh[t];
            const float n2 = us * us * NS_sh[c];
            const float f = squash_scale(n2) * us;
            float4* o4 = (float4*)(out + (((b * 64 + t) * 16 + c) << 4));
            const float4* s4 = (const float4*)(S_sh + c * 16);
#pragma unroll
            for (int q = 0; q < 4; ++q) {
                const float4 sv = s4[q];
                float4 ov;
                ov.x = f * sv.x; ov.y = f * sv.y; ov.z = f * sv.z; ov.w = f * sv.w;
                o4[q] = ov;
            }
        }
    }
}

extern "C" void kernel_launch(void* const* d_in, const int* in_sizes, int n_in,
                              void* d_out, int out_size, void* d_ws, size_t ws_size,
                              hipStream_t stream) {
    const float* ui = (const float*)d_in[0];   // [16,64,16]
    const float* W  = (const float*)d_in[1];   // [1,256,16,16,16]
    float* out = (float*)d_out;                // [16,64,16,16]
    float* ws  = (float*)d_ws;

    k1_prep<<<256, 256, 0, stream>>>(W, ws);
    k2_route<<<16, 1024, 0, stream>>>(ui, ws, out);
}

// Round 7
// 46.116 us; speedup vs baseline: 2.3545x; 1.0708x over previous
//
#include <hip/hip_runtime.h>
#include <math.h>

// B=16, T=64, R=256, C=16, D=16, O(=in_dim)=16, NUM_ITERATIONS=3
//
// Factorization: u_hat[b,t,r,c,o] = Wsum[r,c,o]*usum[b,t]
//   Wsum[r,c,o] = sum_d W[r,c,d,o], usum[b,t] = sum_i ui[b,t,i]
// Per iter: cij = softmax_c(bij); S[c,o] = sum_r cij[r,c]*Wsum[r,c,o]
//   NS[c] = sum_o S^2; Ts[c] = sum_t us^2*squash_scale(us^2*NS[c])
//   bij[r,c] += (sum_o Wsum[r,c,o]*S[c,o]) * Ts[c]
// Output: v[b,t,c,o] = squash_scale(us^2*NS[c])*us*S[c,o]
//
// R6 lesson: rolled scalar-LDS loops (ds_read latency ~120cy each) made the
// LDS-cached variant 50us. Back to R4's streaming structure, fully unrolled
// float4, shfl reductions, bij/cij in LDS, it0 closed-form (no init pass).

#define OFF_WS 0       // Wsum  [r][co]  256x256
#define OFF_WT 65536   // WsumT [co][r]  256x256

__device__ __forceinline__ float squash_scale(float n2) {
    return n2 / (1.0f + n2) * rsqrtf(n2 + 1e-9f);
}

// K1: both Wsum layouts. grid 256x256.
__global__ void k1_prep(const float* __restrict__ W, float* __restrict__ ws) {
    const int r = blockIdx.x, tid = threadIdx.x;   // tid = c*16+o
    const int c = tid >> 4, o = tid & 15;
    const float* base = W + r * 4096 + c * 256 + o;
    float s = 0.f;
#pragma unroll
    for (int d = 0; d < 16; ++d) s += base[d * 16];
    ws[OFF_WS + r * 256 + tid] = s;
    ws[OFF_WT + tid * 256 + r] = s;
}

// K2: full routing, one block per b. grid 16 x 1024.
__global__ void __launch_bounds__(1024, 1) k2_route(
    const float* __restrict__ ui, const float* __restrict__ ws,
    float* __restrict__ out)
{
    __shared__ float bij[256][20];                   // [r][c], stride 20 (16B-aligned rows)
    __shared__ __align__(16) float cijT[16][260];    // [c][r]
    __shared__ __align__(16) float S_sh[256];        // [c*16+o]
    __shared__ float Ts_sh[16];
    __shared__ float usum_sh[64];

    const int b = blockIdx.x, tid = threadIdx.x;
    const int wv = tid >> 6, ln = tid & 63;          // wave id (=c in B/D), lane

    if (tid < 64) {
        const float4* u4 = (const float4*)(ui + b * 1024 + tid * 16);
        float4 a = u4[0], e = u4[1], f = u4[2], g = u4[3];
        usum_sh[tid] = ((a.x + a.y) + (a.z + a.w)) + ((e.x + e.y) + (e.z + e.w))
                     + ((f.x + f.y) + (f.z + f.w)) + ((g.x + g.y) + (g.z + g.w));
    }

    for (int it = 0; it < 3; ++it) {
        // A: softmax over c of bij[r,:] -> cijT[c][r]  (skip it0: uniform)
        if (it > 0) {
            if (tid < 256) {
                float v[16];
                float4* rv = (float4*)v;
                const float4* bp = (const float4*)bij[tid];
#pragma unroll
                for (int q = 0; q < 4; ++q) rv[q] = bp[q];
                float m = v[0];
#pragma unroll
                for (int c = 1; c < 16; ++c) m = fmaxf(m, v[c]);
                float z = 0.f;
#pragma unroll
                for (int c = 0; c < 16; ++c) { v[c] = __expf(v[c] - m); z += v[c]; }
                const float inv = 1.0f / z;
#pragma unroll
                for (int c = 0; c < 16; ++c) cijT[c][tid] = v[c] * inv;
            }
            __syncthreads();
        }

        // B: S[c,o] = sum_r cij[r,c]*WsumT[co][r]; wave wv = c, lane=(o,rs)
        {
            const int c = wv, o = ln >> 2, rs = ln & 3;
            const float4* wt = (const float4*)(ws + OFF_WT + (c * 16 + o) * 256 + rs * 64);
            float acc = 0.f;
            if (it == 0) {
#pragma unroll
                for (int q = 0; q < 16; ++q) {
                    const float4 w = wt[q];
                    acc += (w.x + w.y) + (w.z + w.w);
                }
            } else {
                const float4* cp = (const float4*)(&cijT[c][rs * 64]);
#pragma unroll
                for (int q = 0; q < 16; ++q) {
                    const float4 w = wt[q];
                    const float4 cv = cp[q];
                    acc += cv.x * w.x + cv.y * w.y + cv.z * w.z + cv.w * w.w;
                }
            }
            acc += __shfl_down(acc, 1, 4);
            acc += __shfl_down(acc, 2, 4);
            if (rs == 0) S_sh[c * 16 + o] = (it == 0) ? acc * (1.0f / 16.0f) : acc;
        }
        __syncthreads();

        if (it < 2) {
            // D: Ts[c]; wave wv = c, lane = t; NS recomputed per lane (broadcast reads)
            {
                const int c = wv;
                float ns = 0.f;
#pragma unroll
                for (int o = 0; o < 16; ++o) { const float s = S_sh[c * 16 + o]; ns += s * s; }
                const float us = usum_sh[ln];
                const float us2 = us * us;
                float v = us2 * squash_scale(us2 * ns);
#pragma unroll
                for (int off = 32; off > 0; off >>= 1) v += __shfl_down(v, off, 64);
                if (ln == 0) Ts_sh[c] = v;
            }
            __syncthreads();
            // E: bij[r][c] (=|+=) (sum_o Wsum[r,co]*S[c,o]) * Ts[c]
#pragma unroll
            for (int k = 0; k < 4; ++k) {
                const int p = k * 1024 + tid;
                const int r = p >> 4, c = p & 15;
                const float4* w4 = (const float4*)(ws + OFF_WS + r * 256 + c * 16);
                const float4* s4 = (const float4*)(S_sh + c * 16);
                float dotv = 0.f;
#pragma unroll
                for (int q = 0; q < 4; ++q) {
                    const float4 w = w4[q];
                    const float4 sv = s4[q];
                    dotv += w.x * sv.x + w.y * sv.y + w.z * sv.z + w.w * sv.w;
                }
                const float v = dotv * Ts_sh[c];
                bij[r][c] = (it == 0) ? v : bij[r][c] + v;
            }
            __syncthreads();
        }
    }

    // Output: v[b,t,c,o] = squash_scale(us^2*NS[c])*us*S[c,o]; thread=(t,c)
    {
        const int t = tid >> 4, c = tid & 15;
        float ns = 0.f;
#pragma unroll
        for (int o = 0; o < 16; ++o) { const float s = S_sh[c * 16 + o]; ns += s * s; }
        const float us = usum_sh[t];
        const float n2 = us * us * ns;
        const float f = squash_scale(n2) * us;
        float4* o4 = (float4*)(out + (((b * 64 + t) * 16 + c) << 4));
        const float4* s4 = (const float4*)(S_sh + c * 16);
#pragma unroll
        for (int q = 0; q < 4; ++q) {
            const float4 sv = s4[q];
            float4 ov;
            ov.x = f * sv.x; ov.y = f * sv.y; ov.z = f * sv.z; ov.w = f * sv.w;
            o4[q] = ov;
        }
    }
}

extern "C" void kernel_launch(void* const* d_in, const int* in_sizes, int n_in,
                              void* d_out, int out_size, void* d_ws, size_t ws_size,
                              hipStream_t stream) {
    const float* ui = (const float*)d_in[0];   // [16,64,16]
    const float* W  = (const float*)d_in[1];   // [1,256,16,16,16]
    float* out = (float*)d_out;                // [16,64,16,16]
    float* ws  = (float*)d_ws;

    k1_prep<<<256, 256, 0, stream>>>(W, ws);
    k2_route<<<16, 1024, 0, stream>>>(ui, ws, out);
}